// Round 3
// baseline (88.084 us; speedup 1.0000x reference)
//
#include <hip/hip_runtime.h>
#include <math.h>

#define TPB 256
#define RB  4096          // reducer blocks (one-shot: 4 float4 of a + 4 of p + 1 of P per thread)
#define TI  2             // Si rows cached in LDS per pair block

__device__ __forceinline__ float waveReduceSum(float v) {
    #pragma unroll
    for (int off = 32; off > 0; off >>= 1)
        v += __shfl_down(v, off, 64);
    return v;
}

// ws layout: [0,RB) = partial sum (a-p)^2 ; [RB,2RB) = partial sum relu(P)^2 ;
//            [2RB, 2RB+PBn) = partial parameter_penalty
__global__ __launch_bounds__(TPB, 4)
void fused_kernel(const float* __restrict__ a,
                  const float* __restrict__ p,
                  const float* __restrict__ Pm,
                  const float* __restrict__ S,
                  const int* __restrict__ ii,
                  const int* __restrict__ jj,
                  float* __restrict__ ws,
                  long nAP, long nP, int Npair, int D, int K, int PBn)
{
    const int wave = threadIdx.x >> 6;
    const int lane = threadIdx.x & 63;

    if ((int)blockIdx.x < PBn) {
        // ---------------- pair role ----------------
        // Block b owns Si rows [b*TI, b*TI+TI); streams all Sj rows once.
        __shared__ float SiL[TI][1024];
        __shared__ float psum[4];
        const int i0 = blockIdx.x * TI;
        const int n4 = D >> 2;                       // 256 float4 per row

        for (int idx = threadIdx.x; idx < TI * n4; idx += TPB) {
            int r = idx / n4, c = idx - r * n4;
            float4 v = make_float4(0.f, 0.f, 0.f, 0.f);
            if (i0 + r < Npair)
                v = ((const float4*)(S + (long)ii[i0 + r] * D))[c];
            ((float4*)SiL[r])[c] = v;
        }
        __syncthreads();

        const int ri0 = (i0     < Npair) ? ii[i0]     : 0;
        const int ri1 = (i0 + 1 < Npair) ? ii[i0 + 1] : 0;

        float local = 0.f;
        const int jPerWave = (Npair + 3) >> 2;
        const int jb = wave * jPerWave;
        const int je = min(Npair, jb + jPerWave);
        for (int j = jb; j < je; ++j) {
            const int rj = jj[j];
            const float4* Sj = (const float4*)(S + (long)rj * D);
            float d20 = 0.f, d21 = 0.f;
            for (int c = lane; c < n4; c += 64) {
                float4 y  = Sj[c];
                float4 x0 = ((const float4*)SiL[0])[c];
                float4 x1 = ((const float4*)SiL[1])[c];
                float e;
                e = x0.x - y.x; d20 += e * e;
                e = x0.y - y.y; d20 += e * e;
                e = x0.z - y.z; d20 += e * e;
                e = x0.w - y.w; d20 += e * e;
                e = x1.x - y.x; d21 += e * e;
                e = x1.y - y.y; d21 += e * e;
                e = x1.z - y.z; d21 += e * e;
                e = x1.w - y.w; d21 += e * e;
            }
            d20 = waveReduceSum(d20);
            d21 = waveReduceSum(d21);
            if (lane == 0) {
                if (i0     < Npair && d20 > 0.f)
                    local += fmaxf(Pm[(long)ri0 * K + rj], 0.f) * sqrtf(d20);
                if (i0 + 1 < Npair && d21 > 0.f)
                    local += fmaxf(Pm[(long)ri1 * K + rj], 0.f) * sqrtf(d21);
            }
        }
        if (lane == 0) psum[wave] = local;
        __syncthreads();
        if (threadIdx.x == 0)
            ws[2 * RB + blockIdx.x] = psum[0] + psum[1] + psum[2] + psum[3];
    } else {
        // ---------------- reducer role (one-shot) ----------------
        const int  rb     = blockIdx.x - PBn;
        const long gtid   = (long)rb * TPB + threadIdx.x;
        const long stride = (long)RB * TPB;           // 1,048,576 threads total

        const float4* a4 = (const float4*)a;
        const float4* p4 = (const float4*)p;
        const long n4  = nAP >> 2;                    // 4,194,304
        const long nP4 = nP  >> 2;                    // 1,048,576

        float s0 = 0.f, s1 = 0.f;
        long i = gtid;
        if (i + 3 * stride < n4) {
            // 8 independent loads, all in flight before any compute
            float4 av0 = a4[i];
            float4 av1 = a4[i + stride];
            float4 av2 = a4[i + 2 * stride];
            float4 av3 = a4[i + 3 * stride];
            float4 pv0 = p4[i];
            float4 pv1 = p4[i + stride];
            float4 pv2 = p4[i + 2 * stride];
            float4 pv3 = p4[i + 3 * stride];
            float d;
            d = av0.x - pv0.x; s0 += d * d;
            d = av0.y - pv0.y; s0 += d * d;
            d = av0.z - pv0.z; s0 += d * d;
            d = av0.w - pv0.w; s0 += d * d;
            d = av1.x - pv1.x; s0 += d * d;
            d = av1.y - pv1.y; s0 += d * d;
            d = av1.z - pv1.z; s0 += d * d;
            d = av1.w - pv1.w; s0 += d * d;
            d = av2.x - pv2.x; s0 += d * d;
            d = av2.y - pv2.y; s0 += d * d;
            d = av2.z - pv2.z; s0 += d * d;
            d = av2.w - pv2.w; s0 += d * d;
            d = av3.x - pv3.x; s0 += d * d;
            d = av3.y - pv3.y; s0 += d * d;
            d = av3.z - pv3.z; s0 += d * d;
            d = av3.w - pv3.w; s0 += d * d;
            i += 4 * stride;
        }
        for (; i < n4; i += stride) {                 // generality tail (empty here)
            float4 av = a4[i], pv = p4[i];
            float d;
            d = av.x - pv.x; s0 += d * d;
            d = av.y - pv.y; s0 += d * d;
            d = av.z - pv.z; s0 += d * d;
            d = av.w - pv.w; s0 += d * d;
        }
        for (long q = gtid; q < nP4; q += stride) {   // exactly 1 iteration here
            float4 v = ((const float4*)Pm)[q];
            float r;
            r = fmaxf(v.x, 0.f); s1 += r * r;
            r = fmaxf(v.y, 0.f); s1 += r * r;
            r = fmaxf(v.z, 0.f); s1 += r * r;
            r = fmaxf(v.w, 0.f); s1 += r * r;
        }

        s0 = waveReduceSum(s0);
        s1 = waveReduceSum(s1);
        __shared__ float sm0[4], sm1[4];
        if (lane == 0) { sm0[wave] = s0; sm1[wave] = s1; }
        __syncthreads();
        if (threadIdx.x == 0) {
            ws[rb]      = sm0[0] + sm0[1] + sm0[2] + sm0[3];
            ws[RB + rb] = sm1[0] + sm1[1] + sm1[2] + sm1[3];
        }
    }
}

__global__ void finalize_kernel(const float* __restrict__ ws,
                                const float* __restrict__ lamb,
                                float* __restrict__ out, int PBn)
{
    float a0 = 0.f, a1 = 0.f, a2 = 0.f;
    const float4* w4 = (const float4*)ws;
    // ws0: RB floats = RB/4 float4 ; ws1 follows contiguously
    for (int i = threadIdx.x; i < RB / 4; i += TPB) {
        float4 v = w4[i];
        a0 += v.x + v.y + v.z + v.w;
        float4 u = w4[RB / 4 + i];
        a1 += u.x + u.y + u.z + u.w;
    }
    for (int i = threadIdx.x; i < PBn; i += TPB)
        a2 += ws[2 * RB + i];

    a0 = waveReduceSum(a0);
    a1 = waveReduceSum(a1);
    a2 = waveReduceSum(a2);

    __shared__ float m0[4], m1[4], m2[4];
    int wave = threadIdx.x >> 6;
    int lane = threadIdx.x & 63;
    if (lane == 0) { m0[wave] = a0; m1[wave] = a1; m2[wave] = a2; }
    __syncthreads();
    if (threadIdx.x == 0) {
        float A0 = m0[0] + m0[1] + m0[2] + m0[3];
        float A1 = m1[0] + m1[1] + m1[2] + m1[3];
        float A2 = m2[0] + m2[1] + m2[2] + m2[3];
        out[0] = sqrtf(A0) + lamb[0] * (sqrtf(A1) + A2);
    }
}

extern "C" void kernel_launch(void* const* d_in, const int* in_sizes, int n_in,
                              void* d_out, int out_size, void* d_ws, size_t ws_size,
                              hipStream_t stream) {
    const float* actual = (const float*)d_in[0];
    const float* pred   = (const float*)d_in[1];
    const float* lamb   = (const float*)d_in[2];
    const float* Pm     = (const float*)d_in[3];
    const float* S      = (const float*)d_in[4];
    const int*   ii     = (const int*)d_in[5];
    const int*   jj     = (const int*)d_in[6];
    float* out = (float*)d_out;
    float* ws  = (float*)d_ws;

    long nAP   = in_sizes[0];                       // 4096*4096
    long nP    = in_sizes[3];                       // 2048*2048
    int  K     = (int)lround(sqrt((double)nP));     // 2048
    int  Npair = in_sizes[5];                       // 128
    int  D     = (int)(in_sizes[4] / K);            // 1024

    int PBn = (Npair + TI - 1) / TI;                // 64 pair blocks

    fused_kernel<<<PBn + RB, TPB, 0, stream>>>(actual, pred, Pm, S, ii, jj, ws,
                                               nAP, nP, Npair, D, K, PBn);
    finalize_kernel<<<1, TPB, 0, stream>>>(ws, lamb, out, PBn);
}

// Round 4
// 78.706 us; speedup vs baseline: 1.1191x; 1.1191x over previous
//
#include <hip/hip_runtime.h>
#include <math.h>

#define TPB 256
#define RBN 1024          // reducer blocks (all-resident, loop with 8-wide batches)
#define TI  4             // Si rows cached in LDS per pair block

__device__ __forceinline__ float waveReduceSum(float v) {
    #pragma unroll
    for (int off = 32; off > 0; off >>= 1)
        v += __shfl_down(v, off, 64);
    return v;
}

// ws layout: [0,RBN) = partials sum (a-p)^2 ; [RBN,2RBN) = partials sum relu(P)^2 ;
//            [2RBN, 2RBN+PBn) = partials parameter_penalty
__global__ __launch_bounds__(TPB, 4)
void fused_kernel(const float* __restrict__ a,
                  const float* __restrict__ p,
                  const float* __restrict__ Pm,
                  const float* __restrict__ S,
                  const int* __restrict__ ii,
                  const int* __restrict__ jj,
                  float* __restrict__ ws,
                  long nAP, long nP, int Npair, int D, int K, int PBn)
{
    const int wave = threadIdx.x >> 6;
    const int lane = threadIdx.x & 63;

    if ((int)blockIdx.x < PBn) {
        // ---------------- pair role ----------------
        // Block pair-id pb: i-group = pb>>1 (TI rows), j-half = pb&1.
        __shared__ float SiL[TI][1024];
        __shared__ float psum[4];
        const int pb    = blockIdx.x;
        const int i0    = (pb >> 1) * TI;
        const int jhalf = pb & 1;
        const int n4    = D >> 2;                    // float4 per row

        for (int idx = threadIdx.x; idx < TI * n4; idx += TPB) {
            int r = idx / n4, c = idx - r * n4;
            float4 v = make_float4(0.f, 0.f, 0.f, 0.f);
            if (i0 + r < Npair)
                v = ((const float4*)(S + (long)ii[i0 + r] * D))[c];
            ((float4*)SiL[r])[c] = v;
        }
        __syncthreads();

        int riv[TI];
        #pragma unroll
        for (int r = 0; r < TI; ++r)
            riv[r] = (i0 + r < Npair) ? ii[i0 + r] : 0;

        const int half = (Npair + 1) >> 1;
        const int jb0  = jhalf * half;
        const int je0  = min(Npair, jb0 + half);
        // split this block's j-range across the 4 waves
        const int perW = (je0 - jb0 + 3) >> 2;
        const int jb   = jb0 + wave * perW;
        const int je   = min(je0, jb + perW);

        float local = 0.f;
        for (int j = jb; j < je; ++j) {
            const int rj = jj[j];
            const float4* Sj = (const float4*)(S + (long)rj * D);
            float d2v[TI];
            #pragma unroll
            for (int r = 0; r < TI; ++r) d2v[r] = 0.f;
            for (int c = lane; c < n4; c += 64) {
                float4 y = Sj[c];
                #pragma unroll
                for (int r = 0; r < TI; ++r) {
                    float4 x = ((const float4*)SiL[r])[c];
                    float e;
                    e = x.x - y.x; d2v[r] += e * e;
                    e = x.y - y.y; d2v[r] += e * e;
                    e = x.z - y.z; d2v[r] += e * e;
                    e = x.w - y.w; d2v[r] += e * e;
                }
            }
            #pragma unroll
            for (int r = 0; r < TI; ++r) {
                float d2 = waveReduceSum(d2v[r]);
                if (lane == 0 && (i0 + r < Npair) && d2 > 0.f)
                    local += fmaxf(Pm[(long)riv[r] * K + rj], 0.f) * sqrtf(d2);
            }
        }
        if (lane == 0) psum[wave] = local;
        __syncthreads();
        if (threadIdx.x == 0)
            ws[2 * RBN + pb] = psum[0] + psum[1] + psum[2] + psum[3];
    } else {
        // ---------------- reducer role ----------------
        const int  rb     = blockIdx.x - PBn;
        const long gtid   = (long)rb * TPB + threadIdx.x;
        const long stride = (long)RBN * TPB;          // 262,144 threads

        const float4* a4 = (const float4*)a;
        const float4* p4 = (const float4*)p;
        const long n4  = nAP >> 2;                    // 4,194,304 -> 16 per thread
        const long nP4 = nP  >> 2;                    // 1,048,576 -> 4 per thread

        float s0 = 0.f, s1 = 0.f;
        long i = gtid;
        // 8-wide batches: 16 independent loads in flight
        for (; i + 7 * stride < n4; i += 8 * stride) {
            float4 av[8], pv[8];
            #pragma unroll
            for (int u = 0; u < 8; ++u) av[u] = a4[i + u * stride];
            #pragma unroll
            for (int u = 0; u < 8; ++u) pv[u] = p4[i + u * stride];
            #pragma unroll
            for (int u = 0; u < 8; ++u) {
                float d;
                d = av[u].x - pv[u].x; s0 += d * d;
                d = av[u].y - pv[u].y; s0 += d * d;
                d = av[u].z - pv[u].z; s0 += d * d;
                d = av[u].w - pv[u].w; s0 += d * d;
            }
        }
        for (; i < n4; i += stride) {
            float4 av = a4[i], pv = p4[i];
            float d;
            d = av.x - pv.x; s0 += d * d;
            d = av.y - pv.y; s0 += d * d;
            d = av.z - pv.z; s0 += d * d;
            d = av.w - pv.w; s0 += d * d;
        }

        long q = gtid;
        for (; q + 3 * stride < nP4; q += 4 * stride) {
            float4 v[4];
            #pragma unroll
            for (int u = 0; u < 4; ++u) v[u] = ((const float4*)Pm)[q + u * stride];
            #pragma unroll
            for (int u = 0; u < 4; ++u) {
                float r;
                r = fmaxf(v[u].x, 0.f); s1 += r * r;
                r = fmaxf(v[u].y, 0.f); s1 += r * r;
                r = fmaxf(v[u].z, 0.f); s1 += r * r;
                r = fmaxf(v[u].w, 0.f); s1 += r * r;
            }
        }
        for (; q < nP4; q += stride) {
            float4 v = ((const float4*)Pm)[q];
            float r;
            r = fmaxf(v.x, 0.f); s1 += r * r;
            r = fmaxf(v.y, 0.f); s1 += r * r;
            r = fmaxf(v.z, 0.f); s1 += r * r;
            r = fmaxf(v.w, 0.f); s1 += r * r;
        }

        s0 = waveReduceSum(s0);
        s1 = waveReduceSum(s1);
        __shared__ float sm0[4], sm1[4];
        if (lane == 0) { sm0[wave] = s0; sm1[wave] = s1; }
        __syncthreads();
        if (threadIdx.x == 0) {
            ws[rb]       = sm0[0] + sm0[1] + sm0[2] + sm0[3];
            ws[RBN + rb] = sm1[0] + sm1[1] + sm1[2] + sm1[3];
        }
    }
}

__global__ void finalize_kernel(const float* __restrict__ ws,
                                const float* __restrict__ lamb,
                                float* __restrict__ out, int PBn)
{
    float a0 = 0.f, a1 = 0.f, a2 = 0.f;
    const float4* w4 = (const float4*)ws;
    for (int i = threadIdx.x; i < RBN / 4; i += TPB) {
        float4 v = w4[i];
        a0 += v.x + v.y + v.z + v.w;
        float4 u = w4[RBN / 4 + i];
        a1 += u.x + u.y + u.z + u.w;
    }
    for (int i = threadIdx.x; i < PBn; i += TPB)
        a2 += ws[2 * RBN + i];

    a0 = waveReduceSum(a0);
    a1 = waveReduceSum(a1);
    a2 = waveReduceSum(a2);

    __shared__ float m0[4], m1[4], m2[4];
    int wave = threadIdx.x >> 6;
    int lane = threadIdx.x & 63;
    if (lane == 0) { m0[wave] = a0; m1[wave] = a1; m2[wave] = a2; }
    __syncthreads();
    if (threadIdx.x == 0) {
        float A0 = m0[0] + m0[1] + m0[2] + m0[3];
        float A1 = m1[0] + m1[1] + m1[2] + m1[3];
        float A2 = m2[0] + m2[1] + m2[2] + m2[3];
        out[0] = sqrtf(A0) + lamb[0] * (sqrtf(A1) + A2);
    }
}

extern "C" void kernel_launch(void* const* d_in, const int* in_sizes, int n_in,
                              void* d_out, int out_size, void* d_ws, size_t ws_size,
                              hipStream_t stream) {
    const float* actual = (const float*)d_in[0];
    const float* pred   = (const float*)d_in[1];
    const float* lamb   = (const float*)d_in[2];
    const float* Pm     = (const float*)d_in[3];
    const float* S      = (const float*)d_in[4];
    const int*   ii     = (const int*)d_in[5];
    const int*   jj     = (const int*)d_in[6];
    float* out = (float*)d_out;
    float* ws  = (float*)d_ws;

    long nAP   = in_sizes[0];                       // 4096*4096
    long nP    = in_sizes[3];                       // 2048*2048
    int  K     = (int)lround(sqrt((double)nP));     // 2048
    int  Npair = in_sizes[5];                       // 128
    int  D     = (int)(in_sizes[4] / K);            // 1024

    int PBn = ((Npair + TI - 1) / TI) * 2;          // 64 pair blocks (j split in halves)

    fused_kernel<<<PBn + RBN, TPB, 0, stream>>>(actual, pred, Pm, S, ii, jj, ws,
                                                nAP, nP, Npair, D, K, PBn);
    finalize_kernel<<<1, TPB, 0, stream>>>(ws, lamb, out, PBn);
}

// Round 5
// 77.785 us; speedup vs baseline: 1.1324x; 1.0119x over previous
//
#include <hip/hip_runtime.h>
#include <math.h>

#define TPB 256
#define RBN 1984          // reducer blocks
#define TI  4             // Si rows cached in LDS per pair block

__device__ __forceinline__ float waveReduceSum(float v) {
    #pragma unroll
    for (int off = 32; off > 0; off >>= 1)
        v += __shfl_down(v, off, 64);
    return v;
}

// ws layout: [0,RBN) = partials sum (a-p)^2 ; [RBN,2RBN) = partials sum relu(P)^2 ;
//            [2RBN, 2RBN+PBn) = partials parameter_penalty
__global__ __launch_bounds__(TPB, 8)
void fused_kernel(const float* __restrict__ a,
                  const float* __restrict__ p,
                  const float* __restrict__ Pm,
                  const float* __restrict__ S,
                  const int* __restrict__ ii,
                  const int* __restrict__ jj,
                  float* __restrict__ ws,
                  long nAP, long nP, int Npair, int D, int K, int PBn)
{
    const int wave = threadIdx.x >> 6;
    const int lane = threadIdx.x & 63;

    if ((int)blockIdx.x < PBn) {
        // ---------------- pair role (64 small blocks, L2-resident S) ----------------
        __shared__ float SiL[TI][1024];
        __shared__ float psum[4];
        const int pb    = blockIdx.x;
        const int i0    = (pb >> 1) * TI;
        const int jhalf = pb & 1;
        const int n4    = D >> 2;

        for (int idx = threadIdx.x; idx < TI * n4; idx += TPB) {
            int r = idx / n4, c = idx - r * n4;
            float4 v = make_float4(0.f, 0.f, 0.f, 0.f);
            if (i0 + r < Npair)
                v = ((const float4*)(S + (long)ii[i0 + r] * D))[c];
            ((float4*)SiL[r])[c] = v;
        }
        __syncthreads();

        int riv[TI];
        #pragma unroll
        for (int r = 0; r < TI; ++r)
            riv[r] = (i0 + r < Npair) ? ii[i0 + r] : 0;

        const int half = (Npair + 1) >> 1;
        const int jb0  = jhalf * half;
        const int je0  = min(Npair, jb0 + half);
        const int perW = (je0 - jb0 + 3) >> 2;
        const int jb   = jb0 + wave * perW;
        const int je   = min(je0, jb + perW);

        float local = 0.f;
        for (int j = jb; j < je; ++j) {
            const int rj = jj[j];
            const float4* Sj = (const float4*)(S + (long)rj * D);
            float d2v[TI];
            #pragma unroll
            for (int r = 0; r < TI; ++r) d2v[r] = 0.f;
            for (int c = lane; c < n4; c += 64) {
                float4 y = Sj[c];
                #pragma unroll
                for (int r = 0; r < TI; ++r) {
                    float4 x = ((const float4*)SiL[r])[c];
                    float e;
                    e = x.x - y.x; d2v[r] += e * e;
                    e = x.y - y.y; d2v[r] += e * e;
                    e = x.z - y.z; d2v[r] += e * e;
                    e = x.w - y.w; d2v[r] += e * e;
                }
            }
            #pragma unroll
            for (int r = 0; r < TI; ++r) {
                float d2 = waveReduceSum(d2v[r]);
                if (lane == 0 && (i0 + r < Npair) && d2 > 0.f)
                    local += fmaxf(Pm[(long)riv[r] * K + rj], 0.f) * sqrtf(d2);
            }
        }
        if (lane == 0) psum[wave] = local;
        __syncthreads();
        if (threadIdx.x == 0)
            ws[2 * RBN + pb] = psum[0] + psum[1] + psum[2] + psum[3];
    } else {
        // ---------------- reducer role (R2-proven 4-wide named batches) ----------------
        const int  rb     = blockIdx.x - PBn;
        const long gtid   = (long)rb * TPB + threadIdx.x;
        const long stride = (long)RBN * TPB;          // 507,904 threads

        const float4* a4 = (const float4*)a;
        const float4* p4 = (const float4*)p;
        const long n4  = nAP >> 2;                    // 4,194,304 -> ~8.26/thread
        const long nP4 = nP  >> 2;                    // 1,048,576 -> ~2.06/thread

        float s0a = 0.f, s0b = 0.f, s0c = 0.f, s0d = 0.f;
        long i = gtid;
        for (; i + 3 * stride < n4; i += 4 * stride) {
            float4 av0 = a4[i];
            float4 av1 = a4[i + stride];
            float4 av2 = a4[i + 2 * stride];
            float4 av3 = a4[i + 3 * stride];
            float4 pv0 = p4[i];
            float4 pv1 = p4[i + stride];
            float4 pv2 = p4[i + 2 * stride];
            float4 pv3 = p4[i + 3 * stride];
            float d;
            d = av0.x - pv0.x; s0a += d * d;
            d = av0.y - pv0.y; s0a += d * d;
            d = av0.z - pv0.z; s0a += d * d;
            d = av0.w - pv0.w; s0a += d * d;
            d = av1.x - pv1.x; s0b += d * d;
            d = av1.y - pv1.y; s0b += d * d;
            d = av1.z - pv1.z; s0b += d * d;
            d = av1.w - pv1.w; s0b += d * d;
            d = av2.x - pv2.x; s0c += d * d;
            d = av2.y - pv2.y; s0c += d * d;
            d = av2.z - pv2.z; s0c += d * d;
            d = av2.w - pv2.w; s0c += d * d;
            d = av3.x - pv3.x; s0d += d * d;
            d = av3.y - pv3.y; s0d += d * d;
            d = av3.z - pv3.z; s0d += d * d;
            d = av3.w - pv3.w; s0d += d * d;
        }
        for (; i < n4; i += stride) {                 // <=1 iteration per thread
            float4 av = a4[i], pv = p4[i];
            float d;
            d = av.x - pv.x; s0a += d * d;
            d = av.y - pv.y; s0a += d * d;
            d = av.z - pv.z; s0a += d * d;
            d = av.w - pv.w; s0a += d * d;
        }

        float s1a = 0.f, s1b = 0.f;
        long q = gtid;
        for (; q + stride < nP4; q += 2 * stride) {
            float4 v0 = ((const float4*)Pm)[q];
            float4 v1 = ((const float4*)Pm)[q + stride];
            float r;
            r = fmaxf(v0.x, 0.f); s1a += r * r;
            r = fmaxf(v0.y, 0.f); s1a += r * r;
            r = fmaxf(v0.z, 0.f); s1a += r * r;
            r = fmaxf(v0.w, 0.f); s1a += r * r;
            r = fmaxf(v1.x, 0.f); s1b += r * r;
            r = fmaxf(v1.y, 0.f); s1b += r * r;
            r = fmaxf(v1.z, 0.f); s1b += r * r;
            r = fmaxf(v1.w, 0.f); s1b += r * r;
        }
        for (; q < nP4; q += stride) {                // <=1 iteration per thread
            float4 v = ((const float4*)Pm)[q];
            float r;
            r = fmaxf(v.x, 0.f); s1a += r * r;
            r = fmaxf(v.y, 0.f); s1a += r * r;
            r = fmaxf(v.z, 0.f); s1a += r * r;
            r = fmaxf(v.w, 0.f); s1a += r * r;
        }

        float s0 = waveReduceSum(s0a + s0b + s0c + s0d);
        float s1 = waveReduceSum(s1a + s1b);
        __shared__ float sm0[4], sm1[4];
        if (lane == 0) { sm0[wave] = s0; sm1[wave] = s1; }
        __syncthreads();
        if (threadIdx.x == 0) {
            ws[rb]       = sm0[0] + sm0[1] + sm0[2] + sm0[3];
            ws[RBN + rb] = sm1[0] + sm1[1] + sm1[2] + sm1[3];
        }
    }
}

__global__ void finalize_kernel(const float* __restrict__ ws,
                                const float* __restrict__ lamb,
                                float* __restrict__ out, int PBn)
{
    float a0 = 0.f, a1 = 0.f, a2 = 0.f;
    const float4* w4 = (const float4*)ws;
    for (int i = threadIdx.x; i < RBN / 4; i += TPB) {
        float4 v = w4[i];
        a0 += v.x + v.y + v.z + v.w;
        float4 u = w4[RBN / 4 + i];
        a1 += u.x + u.y + u.z + u.w;
    }
    for (int i = threadIdx.x; i < PBn; i += TPB)
        a2 += ws[2 * RBN + i];

    a0 = waveReduceSum(a0);
    a1 = waveReduceSum(a1);
    a2 = waveReduceSum(a2);

    __shared__ float m0[4], m1[4], m2[4];
    int wave = threadIdx.x >> 6;
    int lane = threadIdx.x & 63;
    if (lane == 0) { m0[wave] = a0; m1[wave] = a1; m2[wave] = a2; }
    __syncthreads();
    if (threadIdx.x == 0) {
        float A0 = m0[0] + m0[1] + m0[2] + m0[3];
        float A1 = m1[0] + m1[1] + m1[2] + m1[3];
        float A2 = m2[0] + m2[1] + m2[2] + m2[3];
        out[0] = sqrtf(A0) + lamb[0] * (sqrtf(A1) + A2);
    }
}

extern "C" void kernel_launch(void* const* d_in, const int* in_sizes, int n_in,
                              void* d_out, int out_size, void* d_ws, size_t ws_size,
                              hipStream_t stream) {
    const float* actual = (const float*)d_in[0];
    const float* pred   = (const float*)d_in[1];
    const float* lamb   = (const float*)d_in[2];
    const float* Pm     = (const float*)d_in[3];
    const float* S      = (const float*)d_in[4];
    const int*   ii     = (const int*)d_in[5];
    const int*   jj     = (const int*)d_in[6];
    float* out = (float*)d_out;
    float* ws  = (float*)d_ws;

    long nAP   = in_sizes[0];                       // 4096*4096
    long nP    = in_sizes[3];                       // 2048*2048
    int  K     = (int)lround(sqrt((double)nP));     // 2048
    int  Npair = in_sizes[5];                       // 128
    int  D     = (int)(in_sizes[4] / K);            // 1024

    int PBn = ((Npair + TI - 1) / TI) * 2;          // 64 pair blocks

    fused_kernel<<<PBn + RBN, TPB, 0, stream>>>(actual, pred, Pm, S, ii, jj, ws,
                                                nAP, nP, Npair, D, K, PBn);
    finalize_kernel<<<1, TPB, 0, stream>>>(ws, lamb, out, PBn);
}